// Round 5
// baseline (432.415 us; speedup 1.0000x reference)
//
#include <hip/hip_runtime.h>
#include <hip/hip_bf16.h>
#include <cmath>

namespace {
constexpr int Pn = 128;
constexpr int Hn = 512;
constexpr int Ln = 8192;
constexpr int BS = 8;
// ws byte layout:
//   [0, 2048)             Lam fp32: [0,128) L_re | [128,256) L_im | [256,384) A64_re | [384,512) A64_im
//   [2048, 264192)        Bmat bf16 [256][512]  (rows 0..127 re, 128..255 im)
//   [264192, 526336)      Cmat bf16 [512][256]  (+2*C_re | -2*C_im)
//   [526336, 591872)      Ppow fp32 [64][256]: [j][p]=Re(L^(j+1)), [j][128+p]=Im(L^(j+1))
//   [591872, 1640448)     End  fp32 [8][128 chunks][2][128]  (chunk-local end states)
//   [1640448, 2689024)    Carry fp32 [8][128 chunks][2][128] (exclusive carries)
//   [2689024, ...)        Bu fp32 [NB][8192][256]  = xlocal, [l][p] layout
constexpr size_t OFF_BMAT = 2048;
constexpr size_t OFF_CMAT = 264192;
constexpr size_t OFF_PPOW = 526336;
constexpr size_t OFF_END  = 591872;
constexpr size_t OFF_CAR  = 1640448;
constexpr size_t HEADB    = 2689024;
constexpr size_t SZ_BU = (size_t)256 * Ln * 4;     // 8388608 per batch
}

typedef __attribute__((ext_vector_type(4))) float f32x4;
typedef __attribute__((ext_vector_type(8))) short bf16x8;
typedef __attribute__((ext_vector_type(4))) short bf16x4;

static __device__ inline short f2bf(float x) {
  __hip_bfloat16 h = __float2bfloat16(x);
  return *(short*)&h;
}

static __device__ inline void async_copy16(const void* g, void* l) {
  __builtin_amdgcn_global_load_lds(
      (const __attribute__((address_space(1))) unsigned int*)g,
      (__attribute__((address_space(3))) unsigned int*)l, 16, 0, 0);
}

// ---------------------------------------------------------------- precompute
__global__ void precompute_kernel(const float* __restrict__ Lre,
                                  const float* __restrict__ Lim,
                                  const float* __restrict__ Bin,
                                  const float* __restrict__ Cin,
                                  const float* __restrict__ lstep,
                                  float* __restrict__ Lam,
                                  __hip_bfloat16* __restrict__ Bmat,
                                  __hip_bfloat16* __restrict__ Cmat,
                                  float* __restrict__ Ppow) {
  int tid = blockIdx.x * blockDim.x + threadIdx.x;
  if (tid < 2 * Pn * Hn) {
    int r = tid >> 9;          // row in [0,256)
    int h = tid & (Hn - 1);
    int p = r & (Pn - 1);
    float st = expf(lstep[p]);
    float lr = Lre[p], li = Lim[p];
    float er = expf(lr * st);
    float cr = er * cosf(li * st);
    float ci = er * sinf(li * st);
    float nr = cr - 1.0f, ni = ci;
    float inv = 1.0f / (lr * lr + li * li);
    float wr = (nr * lr + ni * li) * inv;
    float wi = (ni * lr - nr * li) * inv;
    float btr = Bin[(p * Hn + h) * 2 + 0];
    float bti = Bin[(p * Hn + h) * 2 + 1];
    float val = (r < Pn) ? (wr * btr - wi * bti) : (wr * bti + wi * btr);
    Bmat[tid] = __float2bfloat16(val);
  } else if (tid < 4 * Pn * Hn) {
    int j = tid - 2 * Pn * Hn;
    int h = j >> 8;
    int c = j & 255;
    int p = c & (Pn - 1);
    float v = (c < Pn) ? 2.0f * Cin[(h * Pn + p) * 2 + 0]
                       : -2.0f * Cin[(h * Pn + p) * 2 + 1];
    Cmat[j] = __float2bfloat16(v);
  } else if (tid < 4 * Pn * Hn + 512) {
    int j = tid - 4 * Pn * Hn;
    int p = j & 127;
    int sel = j >> 7;   // 0: L_re  1: L_im  2: A64_re  3: A64_im
    float st = expf(lstep[p]);
    float lr = Lre[p], li = Lim[p];
    float sc = (sel < 2) ? st : 64.0f * st;
    float er = expf(lr * sc);
    Lam[(sel >> 1) * 256 + (sel & 1) * 128 + p] =
        (sel & 1) ? er * sinf(li * sc) : er * cosf(li * sc);
  } else if (tid < 4 * Pn * Hn + 512 + 64 * 256) {
    int j = tid - 4 * Pn * Hn - 512;    // 0..16383
    int jr = j >> 8;                    // 0..63
    int k = j & 255;
    int p = k & 127;
    float st = expf(lstep[p]);
    float lr = Lre[p], li = Lim[p];
    float tt = st * (float)(jr + 1);
    float er = expf(lr * tt);
    Ppow[j] = (k < 128) ? er * cosf(li * tt) : er * sinf(li * tt);
  }
}

// ---------------------------------------------------------------- MFMA GEMM1 + fused chunk-local scan
// Per block: computes [256 p][64 l] tile of Bmat @ U, then scans over its 64 l's
// (chunk == block) with x_{-1}=0, writes xlocal to Bu [l][p] and End[chunk].
__global__ __launch_bounds__(256) void gemm1_kernel(
    const __hip_bfloat16* __restrict__ Amat,  // [256][512]
    const float* __restrict__ U,              // [8][512][8192]
    float* __restrict__ Bu,                   // [NB][8192][256] xlocal
    float* __restrict__ End,                  // [NB][128][2][128]
    const float* __restrict__ Lam,
    int b0) {
  __shared__ __align__(16) char shm[33280];          // 32*260*4
  short* As = (short*)shm;                           // 16 KB (mainloop)
  short* Bsb = (short*)(shm + 16384);                // 5 KB  (mainloop)
  float (*Sl)[260] = (float(*)[260])shm;             // 33.3 KB (epilogue, aliased)
  const int t = threadIdx.x;
  const int lane = t & 63, w = t >> 6;
  const int n0 = blockIdx.x * 64;
  const int bz = blockIdx.z;
  const float* Ub = U + (size_t)(b0 + bz) * Hn * Ln;

  const int srow = lane >> 2, scol = (lane & 3) * 16;  // A staging
  const int bn = t & 63, bkg = t >> 6;                 // B staging
  const int lr = lane & 15, lk = (lane >> 4) * 8;

  f32x4 acc[4][4] = {};
  for (int k0 = 0; k0 < Hn; k0 += 32) {
#pragma unroll
    for (int I2 = 0; I2 < 4; I2++) {
      int I = 4 * w + I2;    // 0..15
      async_copy16((const char*)(Amat + (size_t)(16 * I + srow) * Hn + k0) + scol,
                   (char*)As + I * 1024);
    }
    {
      float v[8];
#pragma unroll
      for (int j = 0; j < 8; j++)
        v[j] = Ub[(size_t)(k0 + bkg * 8 + j) * Ln + n0 + bn];
      bf16x8 pk;
#pragma unroll
      for (int j = 0; j < 8; j++) pk[j] = f2bf(v[j]);
      *(bf16x8*)&Bsb[bn * 40 + bkg * 8] = pk;
    }
    __syncthreads();
    bf16x8 af[4], bfr[4];
#pragma unroll
    for (int mt = 0; mt < 4; mt++)
      af[mt] = *(const bf16x8*)&As[(64 * w + 16 * mt + lr) * 32 + lk];
#pragma unroll
    for (int nt = 0; nt < 4; nt++)
      bfr[nt] = *(const bf16x8*)&Bsb[(16 * nt + lr) * 40 + lk];
#pragma unroll
    for (int mt = 0; mt < 4; mt++)
#pragma unroll
      for (int nt = 0; nt < 4; nt++)
        acc[mt][nt] = __builtin_amdgcn_mfma_f32_16x16x32_bf16(
            af[mt], bfr[nt], acc[mt][nt], 0, 0, 0);
    __syncthreads();
  }

  // ---- fused epilogue: transpose to LDS, chunk-local scan, write xlocal + End.
  const int row4 = (lane >> 4) * 4, col = lane & 15;
  float* Bub = Bu + (size_t)bz * Ln * 256;
  float scr = 0.f, sci = 0.f;         // scan state (threads t<128: complex p=t)
  const float Ar = Lam[t & 127], Ai = Lam[128 + (t & 127)];
#pragma unroll
  for (int pass = 0; pass < 2; pass++) {
    __syncthreads();
    // acc -> Sl[n_local][m] (n_local = l within pass's 32 rows)
#pragma unroll
    for (int mt = 0; mt < 4; mt++)
#pragma unroll
      for (int ntl = 0; ntl < 2; ntl++) {
        int nt = 2 * pass + ntl;
        *(f32x4*)&Sl[16 * ntl + col][64 * w + 16 * mt + row4] = acc[mt][nt];
      }
    __syncthreads();
    if (t < 128) {
      const int p = t;
#pragma unroll
      for (int j = 0; j < 32; j++) {
        float br = Sl[j][p], bi = Sl[j][128 + p];
        float nr = fmaf(Ar, scr, fmaf(-Ai, sci, br));
        float ni = fmaf(Ar, sci, fmaf(Ai, scr, bi));
        scr = nr; sci = ni;
        Sl[j][p] = nr; Sl[j][128 + p] = ni;
      }
    }
    __syncthreads();
    // coalesced store: 32 rows x 1KB
    {
      const int row = t >> 3, seg = t & 7;
      float* dst = Bub + (size_t)(n0 + 32 * pass + row) * 256 + seg * 32;
      const float* src = &Sl[row][seg * 32];
#pragma unroll
      for (int q = 0; q < 8; q++)
        *(f32x4*)&dst[4 * q] = *(const f32x4*)&src[4 * q];
    }
  }
  if (t < 128) {
    float* E = End + ((size_t)bz * 128 + blockIdx.x) * 256;
    E[t] = scr;
    E[128 + t] = sci;
  }
}

// ---------------------------------------------------------------- carry propagation (A64, 128 chunks)
__global__ __launch_bounds__(128) void carry_kernel(const float* __restrict__ End,
                                                    float* __restrict__ Carry,
                                                    const float* __restrict__ Lam) {
  const int bz = blockIdx.x;
  const int p = threadIdx.x;
  const float a64r = Lam[256 + p], a64i = Lam[384 + p];
  const float* E = End + (size_t)bz * 128 * 256;
  float* C = Carry + (size_t)bz * 128 * 256;
  float xr = 0.f, xi = 0.f;
  float er0[4], ei0[4], er1[4], ei1[4];
#pragma unroll
  for (int q = 0; q < 4; q++) {
    er0[q] = E[(size_t)q * 256 + p];
    ei0[q] = E[(size_t)q * 256 + 128 + p];
  }
  for (int c0 = 0; c0 < 128; c0 += 8) {
#pragma unroll
    for (int q = 0; q < 4; q++) {
      er1[q] = E[(size_t)(c0 + 4 + q) * 256 + p];
      ei1[q] = E[(size_t)(c0 + 4 + q) * 256 + 128 + p];
    }
#pragma unroll
    for (int q = 0; q < 4; q++) {
      C[(size_t)(c0 + q) * 256 + p] = xr;
      C[(size_t)(c0 + q) * 256 + 128 + p] = xi;
      float nr = fmaf(a64r, xr, fmaf(-a64i, xi, er0[q]));
      float ni = fmaf(a64r, xi, fmaf(a64i, xr, ei0[q]));
      xr = nr; xi = ni;
    }
#pragma unroll
    for (int q = 0; q < 4; q++) {
      int cn = c0 + 8 + q;
      if (cn < 128) {
        er0[q] = E[(size_t)cn * 256 + p];
        ei0[q] = E[(size_t)cn * 256 + 128 + p];
      }
    }
#pragma unroll
    for (int q = 0; q < 4; q++) {
      C[(size_t)(c0 + 4 + q) * 256 + p] = xr;
      C[(size_t)(c0 + 4 + q) * 256 + 128 + p] = xi;
      float nr = fmaf(a64r, xr, fmaf(-a64i, xi, er1[q]));
      float ni = fmaf(a64r, xi, fmaf(a64i, xr, ei1[q]));
      xr = nr; xi = ni;
    }
  }
}

// ---------------------------------------------------------------- MFMA GEMM2 + fused scan reconstruction
// Prologue: xs = Ppow[l&63]*carry[l>>6] + xlocal[l], cast bf16 into persistent
// LDS B-tile [128][264]. Mainloop: A direct from global (L2-hot Cmat), B from
// LDS — zero barriers.
__global__ __launch_bounds__(256) void gemm2_kernel(
    const __hip_bfloat16* __restrict__ Cmat,  // [512][256]
    const float* __restrict__ Xs,             // [NB][8192][256] xlocal fp32
    const float* __restrict__ Ppow,           // [64][256]
    const float* __restrict__ Cy,             // [NB][128][2][128]
    const float* __restrict__ U,              // [8][512][8192]
    const float* __restrict__ Dv,             // [512]
    float* __restrict__ Out, int b0) {
  __shared__ __align__(16) short BsF[128 * 264];   // 67.6 KB persistent B-tile
  const int t = threadIdx.x;
  const int lane = t & 63, w = t >> 6;
  const int wm = w >> 1, wn = w & 1;
  const int n0 = blockIdx.x * 128;
  const int m0 = blockIdx.y * 128;
  const int bz = blockIdx.z;
  const int b = b0 + bz;
  const short* Ap = (const short*)Cmat;
  const float* Xb = Xs + ((size_t)bz * Ln + n0) * 256;

  // ---- prologue: reconstruct + cvt B-tile
  {
    const int kc = (t & 63) * 4;        // fixed 4-k window per thread
    const int rb = t >> 6;              // row base 0..3
    const bool isRe = kc < 128;
    const int p0 = kc & 127;
    const float sgn = isRe ? -1.f : 1.f;
    const float* Cyb = Cy + ((size_t)bz * 128 + 2 * blockIdx.x) * 256;
    f32x4 ca[2], cb[2];
#pragma unroll
    for (int ch = 0; ch < 2; ch++) {
      f32x4 cre = *(const f32x4*)&Cyb[ch * 256 + p0];
      f32x4 cim = *(const f32x4*)&Cyb[ch * 256 + 128 + p0];
      ca[ch] = isRe ? cre : cim;
      f32x4 cbv = isRe ? cim : cre;
      cb[ch] = cbv * sgn;               // sign folded: re: -im, im: +re
    }
#pragma unroll
    for (int h = 0; h < 2; h++) {
#pragma unroll
      for (int i2 = 0; i2 < 16; i2++) {
        int r = 64 * h + rb + 4 * i2;   // 0..127, wave-uniform
        int j = rb + 4 * i2;            // r & 63
        f32x4 v = *(const f32x4*)&Xb[(size_t)r * 256 + kc];
        f32x4 Pre = *(const f32x4*)&Ppow[j * 256 + p0];
        f32x4 Pim = *(const f32x4*)&Ppow[j * 256 + 128 + p0];
#pragma unroll
        for (int q = 0; q < 4; q++)
          v[q] = fmaf(Pre[q], ca[h][q], fmaf(Pim[q], cb[h][q], v[q]));
        bf16x4 pk;
#pragma unroll
        for (int q = 0; q < 4; q++) pk[q] = f2bf(v[q]);
        *(bf16x4*)&BsF[r * 264 + kc] = pk;
      }
    }
  }
  __syncthreads();

  // ---- mainloop: no barriers
  const int lr = lane & 15, lk = (lane >> 4) * 8;
  f32x4 acc[4][4] = {};
#pragma unroll
  for (int ks = 0; ks < 8; ks++) {
    const int k0 = ks * 32;
    bf16x8 af[4], bfr[4];
#pragma unroll
    for (int mt = 0; mt < 4; mt++)
      af[mt] = *(const bf16x8*)&Ap[(size_t)(m0 + 64 * wm + 16 * mt + lr) * 256 + k0 + lk];
#pragma unroll
    for (int nt = 0; nt < 4; nt++)
      bfr[nt] = *(const bf16x8*)&BsF[(64 * wn + 16 * nt + lr) * 264 + k0 + lk];
#pragma unroll
    for (int mt = 0; mt < 4; mt++)
#pragma unroll
      for (int nt = 0; nt < 4; nt++)
        acc[mt][nt] = __builtin_amdgcn_mfma_f32_16x16x32_bf16(
            af[mt], bfr[nt], acc[mt][nt], 0, 0, 0);
  }

  const int row4 = (lane >> 4) * 4, col = lane & 15;
#pragma unroll
  for (int mt = 0; mt < 4; mt++) {
#pragma unroll
    for (int r = 0; r < 4; r++) {
      int h = m0 + 64 * wm + 16 * mt + row4 + r;
      float dh = Dv[h];
      const float* Urow = U + ((size_t)b * Hn + h) * Ln;
      float* Orow = Out + ((size_t)b * Hn + h) * Ln;
#pragma unroll
      for (int nt = 0; nt < 4; nt++) {
        int n = n0 + 64 * wn + 16 * nt + col;
        float y = acc[mt][nt][r] + dh * Urow[n];
        // tanh-form gelu: y * sigmoid(2*0.7978845608*(y + 0.044715 y^3)), tail-safe
        float u2 = y * (0.7978845608f + 0.0356774081f * y * y);
        Orow[n] = y / (1.0f + __expf(-2.0f * u2));
      }
    }
  }
}

// ---------------------------------------------------------------- launch
extern "C" void kernel_launch(void* const* d_in, const int* in_sizes, int n_in,
                              void* d_out, int out_size, void* d_ws, size_t ws_size,
                              hipStream_t stream) {
  const float* U   = (const float*)d_in[0];
  const float* Lre = (const float*)d_in[1];
  const float* Lim = (const float*)d_in[2];
  const float* Bin = (const float*)d_in[3];
  const float* Cin = (const float*)d_in[4];
  const float* Dv  = (const float*)d_in[5];
  const float* ls  = (const float*)d_in[6];
  float* out = (float*)d_out;

  char* wsb = (char*)d_ws;
  float* Lam = (float*)wsb;
  __hip_bfloat16* Bmat = (__hip_bfloat16*)(wsb + OFF_BMAT);
  __hip_bfloat16* Cmat = (__hip_bfloat16*)(wsb + OFF_CMAT);
  float* Ppow = (float*)(wsb + OFF_PPOW);
  float* End = (float*)(wsb + OFF_END);
  float* Cy  = (float*)(wsb + OFF_CAR);
  float* Bu  = (float*)(wsb + HEADB);

  int NB = 8;
  while (NB > 1 && ws_size < HEADB + (size_t)NB * SZ_BU)
    NB >>= 1;

  precompute_kernel<<<(4 * Pn * Hn + 512 + 64 * 256 + 255) / 256, 256, 0, stream>>>(
      Lre, Lim, Bin, Cin, ls, Lam, Bmat, Cmat, Ppow);

  for (int b0 = 0; b0 < BS; b0 += NB) {
    gemm1_kernel<<<dim3(Ln / 64, 1, NB), 256, 0, stream>>>(Bmat, U, Bu, End, Lam, b0);
    carry_kernel<<<dim3(NB), 128, 0, stream>>>(End, Cy, Lam);
    gemm2_kernel<<<dim3(Ln / 128, Hn / 128, NB), 256, 0, stream>>>(
        Cmat, Bu, Ppow, Cy, U, Dv, out, b0);
  }
}

// Round 6
// 352.354 us; speedup vs baseline: 1.2272x; 1.2272x over previous
//
#include <hip/hip_runtime.h>
#include <hip/hip_bf16.h>
#include <cmath>

namespace {
constexpr int Pn = 128;
constexpr int Hn = 512;
constexpr int Ln = 8192;
constexpr int BS = 8;
// ws byte layout:
//   [0, 2048)             Lam fp32: [0,128) L_re | [128,256) L_im | [256,384) A64_re | [384,512) A64_im
//   [2048, 264192)        Bmat bf16 [256][512]  (rows 0..127 re, 128..255 im)
//   [264192, 526336)      Cmat bf16 [512][256]  (+2*C_re | -2*C_im)
//   [526336, 591872)      Ppow fp32 [64][256]: [j][p]=Re(L^(j+1)), [j][128+p]=Im(L^(j+1))
//   [591872, 1640448)     End  fp32 [8][128 chunks][2][128]  (chunk-local end states)
//   [1640448, 2689024)    Carry fp32 [8][128 chunks][2][128] (exclusive carries)
//   [2689024, ...)        Bu bf16 [NB][8192][256] = xlocal, [l][p] rows (512 B)
constexpr size_t OFF_BMAT = 2048;
constexpr size_t OFF_CMAT = 264192;
constexpr size_t OFF_PPOW = 526336;
constexpr size_t OFF_END  = 591872;
constexpr size_t OFF_CAR  = 1640448;
constexpr size_t HEADB    = 2689024;
constexpr size_t SZ_BU = (size_t)256 * Ln * 2;     // 4 MB per batch (bf16)
}

typedef __attribute__((ext_vector_type(4))) float f32x4;
typedef __attribute__((ext_vector_type(8))) short bf16x8;

static __device__ inline short f2bf(float x) {
  __hip_bfloat16 h = __float2bfloat16(x);
  return *(short*)&h;
}
static __device__ inline float bf2f(short s) {
  unsigned u = ((unsigned)(unsigned short)s) << 16;
  return __uint_as_float(u);
}

static __device__ inline void async_copy16(const void* g, void* l) {
  __builtin_amdgcn_global_load_lds(
      (const __attribute__((address_space(1))) unsigned int*)g,
      (__attribute__((address_space(3))) unsigned int*)l, 16, 0, 0);
}

// ---------------------------------------------------------------- precompute
__global__ void precompute_kernel(const float* __restrict__ Lre,
                                  const float* __restrict__ Lim,
                                  const float* __restrict__ Bin,
                                  const float* __restrict__ Cin,
                                  const float* __restrict__ lstep,
                                  float* __restrict__ Lam,
                                  __hip_bfloat16* __restrict__ Bmat,
                                  __hip_bfloat16* __restrict__ Cmat,
                                  float* __restrict__ Ppow) {
  int tid = blockIdx.x * blockDim.x + threadIdx.x;
  if (tid < 2 * Pn * Hn) {
    int r = tid >> 9;          // row in [0,256)
    int h = tid & (Hn - 1);
    int p = r & (Pn - 1);
    float st = expf(lstep[p]);
    float lr = Lre[p], li = Lim[p];
    float er = expf(lr * st);
    float cr = er * cosf(li * st);
    float ci = er * sinf(li * st);
    float nr = cr - 1.0f, ni = ci;
    float inv = 1.0f / (lr * lr + li * li);
    float wr = (nr * lr + ni * li) * inv;
    float wi = (ni * lr - nr * li) * inv;
    float btr = Bin[(p * Hn + h) * 2 + 0];
    float bti = Bin[(p * Hn + h) * 2 + 1];
    float val = (r < Pn) ? (wr * btr - wi * bti) : (wr * bti + wi * btr);
    Bmat[tid] = __float2bfloat16(val);
  } else if (tid < 4 * Pn * Hn) {
    int j = tid - 2 * Pn * Hn;
    int h = j >> 8;
    int c = j & 255;
    int p = c & (Pn - 1);
    float v = (c < Pn) ? 2.0f * Cin[(h * Pn + p) * 2 + 0]
                       : -2.0f * Cin[(h * Pn + p) * 2 + 1];
    Cmat[j] = __float2bfloat16(v);
  } else if (tid < 4 * Pn * Hn + 512) {
    int j = tid - 4 * Pn * Hn;
    int p = j & 127;
    int sel = j >> 7;   // 0: L_re  1: L_im  2: A64_re  3: A64_im
    float st = expf(lstep[p]);
    float lr = Lre[p], li = Lim[p];
    float sc = (sel < 2) ? st : 64.0f * st;
    float er = expf(lr * sc);
    Lam[(sel >> 1) * 256 + (sel & 1) * 128 + p] =
        (sel & 1) ? er * sinf(li * sc) : er * cosf(li * sc);
  } else if (tid < 4 * Pn * Hn + 512 + 64 * 256) {
    int j = tid - 4 * Pn * Hn - 512;    // 0..16383
    int jr = j >> 8;                    // 0..63
    int k = j & 255;
    int p = k & 127;
    float st = expf(lstep[p]);
    float lr = Lre[p], li = Lim[p];
    float tt = st * (float)(jr + 1);
    float er = expf(lr * tt);
    Ppow[j] = (k < 128) ? er * cosf(li * tt) : er * sinf(li * tt);
  }
}

// ---------------------------------------------------------------- MFMA GEMM1 + fused chunk-local scan
// Per block: computes [256 p][64 l] tile of Bmat @ U, then scans over its 64 l's
// (chunk == block) with x_{-1}=0, writes xlocal (bf16) to Bu [l][p] and End[chunk].
__global__ __launch_bounds__(256) void gemm1_kernel(
    const __hip_bfloat16* __restrict__ Amat,  // [256][512]
    const float* __restrict__ U,              // [8][512][8192]
    short* __restrict__ Bu,                   // [NB][8192][256] xlocal bf16
    float* __restrict__ End,                  // [NB][128][2][128]
    const float* __restrict__ Lam,
    int b0) {
  __shared__ __align__(16) char shm[33280];          // 32*260*4
  short* As = (short*)shm;                           // 16 KB (mainloop)
  short* Bsb = (short*)(shm + 16384);                // 5 KB  (mainloop)
  float (*Sl)[260] = (float(*)[260])shm;             // 33.3 KB (epilogue, aliased)
  const int t = threadIdx.x;
  const int lane = t & 63, w = t >> 6;
  const int n0 = blockIdx.x * 64;
  const int bz = blockIdx.z;
  const float* Ub = U + (size_t)(b0 + bz) * Hn * Ln;

  const int srow = lane >> 2, scol = (lane & 3) * 16;  // A staging
  const int bn = t & 63, bkg = t >> 6;                 // B staging
  const int lr = lane & 15, lk = (lane >> 4) * 8;

  f32x4 acc[4][4] = {};
  for (int k0 = 0; k0 < Hn; k0 += 32) {
#pragma unroll
    for (int I2 = 0; I2 < 4; I2++) {
      int I = 4 * w + I2;    // 0..15
      async_copy16((const char*)(Amat + (size_t)(16 * I + srow) * Hn + k0) + scol,
                   (char*)As + I * 1024);
    }
    {
      float v[8];
#pragma unroll
      for (int j = 0; j < 8; j++)
        v[j] = Ub[(size_t)(k0 + bkg * 8 + j) * Ln + n0 + bn];
      bf16x8 pk;
#pragma unroll
      for (int j = 0; j < 8; j++) pk[j] = f2bf(v[j]);
      *(bf16x8*)&Bsb[bn * 40 + bkg * 8] = pk;
    }
    __syncthreads();
    bf16x8 af[4], bfr[4];
#pragma unroll
    for (int mt = 0; mt < 4; mt++)
      af[mt] = *(const bf16x8*)&As[(64 * w + 16 * mt + lr) * 32 + lk];
#pragma unroll
    for (int nt = 0; nt < 4; nt++)
      bfr[nt] = *(const bf16x8*)&Bsb[(16 * nt + lr) * 40 + lk];
#pragma unroll
    for (int mt = 0; mt < 4; mt++)
#pragma unroll
      for (int nt = 0; nt < 4; nt++)
        acc[mt][nt] = __builtin_amdgcn_mfma_f32_16x16x32_bf16(
            af[mt], bfr[nt], acc[mt][nt], 0, 0, 0);
    __syncthreads();
  }

  // ---- fused epilogue: transpose to LDS, chunk-local scan, write xlocal (bf16) + End.
  const int row4 = (lane >> 4) * 4, col = lane & 15;
  short* Bub = Bu + (size_t)bz * Ln * 256;
  float scr = 0.f, sci = 0.f;         // scan state (threads t<128: complex p=t)
  const float Ar = Lam[t & 127], Ai = Lam[128 + (t & 127)];
#pragma unroll
  for (int pass = 0; pass < 2; pass++) {
    __syncthreads();
    // acc -> Sl[n_local][m] (n_local = l within pass's 32 rows)
#pragma unroll
    for (int mt = 0; mt < 4; mt++)
#pragma unroll
      for (int ntl = 0; ntl < 2; ntl++) {
        int nt = 2 * pass + ntl;
        *(f32x4*)&Sl[16 * ntl + col][64 * w + 16 * mt + row4] = acc[mt][nt];
      }
    __syncthreads();
    if (t < 128) {
      const int p = t;
#pragma unroll
      for (int j = 0; j < 32; j++) {
        float br = Sl[j][p], bi = Sl[j][128 + p];
        float nr = fmaf(Ar, scr, fmaf(-Ai, sci, br));
        float ni = fmaf(Ar, sci, fmaf(Ai, scr, bi));
        scr = nr; sci = ni;
        Sl[j][p] = nr; Sl[j][128 + p] = ni;
      }
    }
    __syncthreads();
    // coalesced bf16 store: 32 rows x 512B
    {
      const int row = t >> 3, seg = t & 7;
      short* dst = Bub + (size_t)(n0 + 32 * pass + row) * 256 + seg * 32;
      const float* src = &Sl[row][seg * 32];
#pragma unroll
      for (int q = 0; q < 4; q++) {
        bf16x8 pk;
#pragma unroll
        for (int j = 0; j < 8; j++) pk[j] = f2bf(src[8 * q + j]);
        *(bf16x8*)&dst[8 * q] = pk;
      }
    }
  }
  if (t < 128) {
    float* E = End + ((size_t)bz * 128 + blockIdx.x) * 256;
    E[t] = scr;
    E[128 + t] = sci;
  }
}

// ---------------------------------------------------------------- carry propagation (A64, 128 chunks)
__global__ __launch_bounds__(128) void carry_kernel(const float* __restrict__ End,
                                                    float* __restrict__ Carry,
                                                    const float* __restrict__ Lam) {
  const int bz = blockIdx.x;
  const int p = threadIdx.x;
  const float a64r = Lam[256 + p], a64i = Lam[384 + p];
  const float* E = End + (size_t)bz * 128 * 256;
  float* C = Carry + (size_t)bz * 128 * 256;
  float xr = 0.f, xi = 0.f;
  float er0[4], ei0[4], er1[4], ei1[4];
#pragma unroll
  for (int q = 0; q < 4; q++) {
    er0[q] = E[(size_t)q * 256 + p];
    ei0[q] = E[(size_t)q * 256 + 128 + p];
  }
  for (int c0 = 0; c0 < 128; c0 += 8) {
#pragma unroll
    for (int q = 0; q < 4; q++) {
      er1[q] = E[(size_t)(c0 + 4 + q) * 256 + p];
      ei1[q] = E[(size_t)(c0 + 4 + q) * 256 + 128 + p];
    }
#pragma unroll
    for (int q = 0; q < 4; q++) {
      C[(size_t)(c0 + q) * 256 + p] = xr;
      C[(size_t)(c0 + q) * 256 + 128 + p] = xi;
      float nr = fmaf(a64r, xr, fmaf(-a64i, xi, er0[q]));
      float ni = fmaf(a64r, xi, fmaf(a64i, xr, ei0[q]));
      xr = nr; xi = ni;
    }
#pragma unroll
    for (int q = 0; q < 4; q++) {
      int cn = c0 + 8 + q;
      if (cn < 128) {
        er0[q] = E[(size_t)cn * 256 + p];
        ei0[q] = E[(size_t)cn * 256 + 128 + p];
      }
    }
#pragma unroll
    for (int q = 0; q < 4; q++) {
      C[(size_t)(c0 + 4 + q) * 256 + p] = xr;
      C[(size_t)(c0 + 4 + q) * 256 + 128 + p] = xi;
      float nr = fmaf(a64r, xr, fmaf(-a64i, xi, er1[q]));
      float ni = fmaf(a64r, xi, fmaf(a64i, xr, ei1[q]));
      xr = nr; xi = ni;
    }
  }
}

// ---------------------------------------------------------------- MFMA GEMM2 (R3 loop + fused recon staging)
// Out[b][H][L] = gelu( Cmat[512][256] @ xs^T + D[h]*U[b][h][l] )
// xs[l] = Ppow[l&63]*carry[l>>6] + xlocal[l], reconstructed per K-step in the
// B-staging phase (Ppow/Cy L2-hot), cvt to bf16 LDS tile. A via async LDS.
__global__ __launch_bounds__(256) void gemm2_kernel(
    const __hip_bfloat16* __restrict__ Cmat,  // [512][256]
    const short* __restrict__ Xs,             // [NB][8192][256] xlocal bf16
    const float* __restrict__ Ppow,           // [64][256]
    const float* __restrict__ Cy,             // [NB][128][2][128]
    const float* __restrict__ U,              // [8][512][8192]
    const float* __restrict__ Dv,             // [512]
    float* __restrict__ Out, int b0) {
  __shared__ __align__(16) short As[128 * 32];   // 8 KB
  __shared__ __align__(16) short Bs[128 * 40];   // 10 KB (stride 40 shorts)
  const int t = threadIdx.x;
  const int lane = t & 63, w = t >> 6;
  const int wm = w >> 1, wn = w & 1;
  const int n0 = blockIdx.x * 128;
  const int m0 = blockIdx.y * 128;
  const int bz = blockIdx.z;
  const int b = b0 + bz;

  const int srow = lane >> 2, scol = (lane & 3) * 16;
  const int krow = t >> 2, kq = t & 3;       // staging: row within 64-group, 16B k-chunk
  const short* Xb = Xs + ((size_t)bz * Ln + n0) * 256;
  const float* Cyb = Cy + ((size_t)bz * 128 + (n0 >> 6)) * 256;

  f32x4 acc[4][4] = {};
  for (int k0 = 0; k0 < 256; k0 += 32) {
#pragma unroll
    for (int I2 = 0; I2 < 2; I2++) {
      int I = 2 * w + I2;
      async_copy16((const char*)(Cmat + (size_t)(m0 + 16 * I + srow) * 256 + k0) + scol,
                   (char*)As + I * 1024);
    }
    // B recon staging: xs = Ppow[row&63]*carry[row>>6] + xlocal, 8 k's per thread per ro
    {
      const int kw = k0 + kq * 8;            // 8 consecutive k, same half (re/im)
      const bool isRe = kw < 128;
      const int p0 = kw & 127;
#pragma unroll
      for (int ro = 0; ro < 2; ro++) {
        const int row = ro * 64 + krow;
        const int j = row & 63;
        bf16x8 xl = *(const bf16x8*)&Xb[(size_t)row * 256 + kw];
        f32x4 Pre0 = *(const f32x4*)&Ppow[j * 256 + p0];
        f32x4 Pre1 = *(const f32x4*)&Ppow[j * 256 + p0 + 4];
        f32x4 Pim0 = *(const f32x4*)&Ppow[j * 256 + 128 + p0];
        f32x4 Pim1 = *(const f32x4*)&Ppow[j * 256 + 128 + p0 + 4];
        f32x4 cr0 = *(const f32x4*)&Cyb[ro * 256 + p0];
        f32x4 cr1 = *(const f32x4*)&Cyb[ro * 256 + p0 + 4];
        f32x4 ci0 = *(const f32x4*)&Cyb[ro * 256 + 128 + p0];
        f32x4 ci1 = *(const f32x4*)&Cyb[ro * 256 + 128 + p0 + 4];
        f32x4 ca0 = isRe ? cr0 : ci0;
        f32x4 ca1 = isRe ? cr1 : ci1;
        f32x4 cb0 = isRe ? -ci0 : cr0;
        f32x4 cb1 = isRe ? -ci1 : cr1;
        bf16x8 pk;
#pragma unroll
        for (int q = 0; q < 4; q++) {
          float v = fmaf(Pre0[q], ca0[q], fmaf(Pim0[q], cb0[q], bf2f(xl[q])));
          pk[q] = f2bf(v);
        }
#pragma unroll
        for (int q = 0; q < 4; q++) {
          float v = fmaf(Pre1[q], ca1[q], fmaf(Pim1[q], cb1[q], bf2f(xl[4 + q])));
          pk[4 + q] = f2bf(v);
        }
        *(bf16x8*)&Bs[row * 40 + kq * 8] = pk;
      }
    }
    __syncthreads();
    const int lr = lane & 15, lk = (lane >> 4) * 8;
    bf16x8 af[4], bfr[4];
#pragma unroll
    for (int mt = 0; mt < 4; mt++)
      af[mt] = *(const bf16x8*)&As[(64 * wm + 16 * mt + lr) * 32 + lk];
#pragma unroll
    for (int nt = 0; nt < 4; nt++)
      bfr[nt] = *(const bf16x8*)&Bs[(64 * wn + 16 * nt + lr) * 40 + lk];
#pragma unroll
    for (int mt = 0; mt < 4; mt++)
#pragma unroll
      for (int nt = 0; nt < 4; nt++)
        acc[mt][nt] = __builtin_amdgcn_mfma_f32_16x16x32_bf16(
            af[mt], bfr[nt], acc[mt][nt], 0, 0, 0);
    __syncthreads();
  }
  const int row4 = (lane >> 4) * 4, col = lane & 15;
#pragma unroll
  for (int mt = 0; mt < 4; mt++) {
#pragma unroll
    for (int r = 0; r < 4; r++) {
      int h = m0 + 64 * wm + 16 * mt + row4 + r;
      float dh = Dv[h];
      const float* Urow = U + ((size_t)b * Hn + h) * Ln;
      float* Orow = Out + ((size_t)b * Hn + h) * Ln;
#pragma unroll
      for (int nt = 0; nt < 4; nt++) {
        int n = n0 + 64 * wn + 16 * nt + col;
        float y = acc[mt][nt][r] + dh * Urow[n];
        // tanh-form gelu: y * sigmoid(2*0.7978845608*(y + 0.044715 y^3)), tail-safe
        float u2 = y * (0.7978845608f + 0.0356774081f * y * y);
        Orow[n] = y / (1.0f + __expf(-2.0f * u2));
      }
    }
  }
}

// ---------------------------------------------------------------- launch
extern "C" void kernel_launch(void* const* d_in, const int* in_sizes, int n_in,
                              void* d_out, int out_size, void* d_ws, size_t ws_size,
                              hipStream_t stream) {
  const float* U   = (const float*)d_in[0];
  const float* Lre = (const float*)d_in[1];
  const float* Lim = (const float*)d_in[2];
  const float* Bin = (const float*)d_in[3];
  const float* Cin = (const float*)d_in[4];
  const float* Dv  = (const float*)d_in[5];
  const float* ls  = (const float*)d_in[6];
  float* out = (float*)d_out;

  char* wsb = (char*)d_ws;
  float* Lam = (float*)wsb;
  __hip_bfloat16* Bmat = (__hip_bfloat16*)(wsb + OFF_BMAT);
  __hip_bfloat16* Cmat = (__hip_bfloat16*)(wsb + OFF_CMAT);
  float* Ppow = (float*)(wsb + OFF_PPOW);
  float* End = (float*)(wsb + OFF_END);
  float* Cy  = (float*)(wsb + OFF_CAR);
  short* Bu  = (short*)(wsb + HEADB);

  int NB = 8;
  while (NB > 1 && ws_size < HEADB + (size_t)NB * SZ_BU)
    NB >>= 1;

  precompute_kernel<<<(4 * Pn * Hn + 512 + 64 * 256 + 255) / 256, 256, 0, stream>>>(
      Lre, Lim, Bin, Cin, ls, Lam, Bmat, Cmat, Ppow);

  for (int b0 = 0; b0 < BS; b0 += NB) {
    gemm1_kernel<<<dim3(Ln / 64, 1, NB), 256, 0, stream>>>(Bmat, U, Bu, End, Lam, b0);
    carry_kernel<<<dim3(NB), 128, 0, stream>>>(End, Cy, Lam);
    gemm2_kernel<<<dim3(Ln / 128, Hn / 128, NB), 256, 0, stream>>>(
        Cmat, Bu, Ppow, Cy, U, Dv, out, b0);
  }
}

// Round 7
// 335.251 us; speedup vs baseline: 1.2898x; 1.0510x over previous
//
#include <hip/hip_runtime.h>
#include <hip/hip_bf16.h>
#include <cmath>

namespace {
constexpr int Pn = 128;
constexpr int Hn = 512;
constexpr int Ln = 8192;
constexpr int BS = 8;
// ws byte layout:
//   [0, 2048)             Lam fp32: [0,128) L_re | [128,256) L_im | [256,384) A64_re | [384,512) A64_im
//   [2048, 264192)        Bmat bf16 [256][512]  (rows 0..127 re, 128..255 im)
//   [264192, 526336)      Cmat bf16 [512][256]  (+2*C_re | -2*C_im)
//   [526336, 591872)      Ppow fp32 [64][256]: [j][p]=Re(L^(j+1)), [j][128+p]=Im(L^(j+1))
//   [591872, 1640448)     End  fp32 [8][128 chunks][2][128]  (chunk-local end states)
//   [1640448, 2689024)    Carry fp32 [8][128 chunks][2][128] (exclusive carries)
//   [2689024, ...)        Bu bf16 [NB][8192][256] = xlocal, [l][p] rows (512 B)
constexpr size_t OFF_BMAT = 2048;
constexpr size_t OFF_CMAT = 264192;
constexpr size_t OFF_PPOW = 526336;
constexpr size_t OFF_END  = 591872;
constexpr size_t OFF_CAR  = 1640448;
constexpr size_t HEADB    = 2689024;
constexpr size_t SZ_BU = (size_t)256 * Ln * 2;     // 4 MB per batch (bf16)
}

typedef __attribute__((ext_vector_type(4))) float f32x4;
typedef __attribute__((ext_vector_type(8))) short bf16x8;

static __device__ inline short f2bf(float x) {
  __hip_bfloat16 h = __float2bfloat16(x);
  return *(short*)&h;
}
static __device__ inline float bf2f(short s) {
  unsigned u = ((unsigned)(unsigned short)s) << 16;
  return __uint_as_float(u);
}

static __device__ inline void async_copy16(const void* g, void* l) {
  __builtin_amdgcn_global_load_lds(
      (const __attribute__((address_space(1))) unsigned int*)g,
      (__attribute__((address_space(3))) unsigned int*)l, 16, 0, 0);
}

// ---------------------------------------------------------------- precompute
__global__ void precompute_kernel(const float* __restrict__ Lre,
                                  const float* __restrict__ Lim,
                                  const float* __restrict__ Bin,
                                  const float* __restrict__ Cin,
                                  const float* __restrict__ lstep,
                                  float* __restrict__ Lam,
                                  __hip_bfloat16* __restrict__ Bmat,
                                  __hip_bfloat16* __restrict__ Cmat,
                                  float* __restrict__ Ppow) {
  int tid = blockIdx.x * blockDim.x + threadIdx.x;
  if (tid < 2 * Pn * Hn) {
    int r = tid >> 9;          // row in [0,256)
    int h = tid & (Hn - 1);
    int p = r & (Pn - 1);
    float st = expf(lstep[p]);
    float lr = Lre[p], li = Lim[p];
    float er = expf(lr * st);
    float cr = er * cosf(li * st);
    float ci = er * sinf(li * st);
    float nr = cr - 1.0f, ni = ci;
    float inv = 1.0f / (lr * lr + li * li);
    float wr = (nr * lr + ni * li) * inv;
    float wi = (ni * lr - nr * li) * inv;
    float btr = Bin[(p * Hn + h) * 2 + 0];
    float bti = Bin[(p * Hn + h) * 2 + 1];
    float val = (r < Pn) ? (wr * btr - wi * bti) : (wr * bti + wi * btr);
    Bmat[tid] = __float2bfloat16(val);
  } else if (tid < 4 * Pn * Hn) {
    int j = tid - 2 * Pn * Hn;
    int h = j >> 8;
    int c = j & 255;
    int p = c & (Pn - 1);
    float v = (c < Pn) ? 2.0f * Cin[(h * Pn + p) * 2 + 0]
                       : -2.0f * Cin[(h * Pn + p) * 2 + 1];
    Cmat[j] = __float2bfloat16(v);
  } else if (tid < 4 * Pn * Hn + 512) {
    int j = tid - 4 * Pn * Hn;
    int p = j & 127;
    int sel = j >> 7;   // 0: L_re  1: L_im  2: A64_re  3: A64_im
    float st = expf(lstep[p]);
    float lr = Lre[p], li = Lim[p];
    float sc = (sel < 2) ? st : 64.0f * st;
    float er = expf(lr * sc);
    Lam[(sel >> 1) * 256 + (sel & 1) * 128 + p] =
        (sel & 1) ? er * sinf(li * sc) : er * cosf(li * sc);
  } else if (tid < 4 * Pn * Hn + 512 + 64 * 256) {
    int j = tid - 4 * Pn * Hn - 512;    // 0..16383
    int jr = j >> 8;                    // 0..63
    int k = j & 255;
    int p = k & 127;
    float st = expf(lstep[p]);
    float lr = Lre[p], li = Lim[p];
    float tt = st * (float)(jr + 1);
    float er = expf(lr * tt);
    Ppow[j] = (k < 128) ? er * cosf(li * tt) : er * sinf(li * tt);
  }
}

// ---------------------------------------------------------------- MFMA GEMM1 + fused chunk-local scan
// Per block: computes [256 p][64 l] tile of Bmat @ U, then scans over its 64 l's
// (chunk == block) with x_{-1}=0, writes xlocal (bf16) to Bu [l][p] and End[chunk].
__global__ __launch_bounds__(256) void gemm1_kernel(
    const __hip_bfloat16* __restrict__ Amat,  // [256][512]
    const float* __restrict__ U,              // [8][512][8192]
    short* __restrict__ Bu,                   // [NB][8192][256] xlocal bf16
    float* __restrict__ End,                  // [NB][128][2][128]
    const float* __restrict__ Lam,
    int b0) {
  __shared__ __align__(16) char shm[33280];          // 32*260*4
  short* As = (short*)shm;                           // 16 KB (mainloop)
  short* Bsb = (short*)(shm + 16384);                // 5 KB  (mainloop)
  float (*Sl)[260] = (float(*)[260])shm;             // 33.3 KB (epilogue, aliased)
  const int t = threadIdx.x;
  const int lane = t & 63, w = t >> 6;
  const int n0 = blockIdx.x * 64;
  const int bz = blockIdx.z;
  const float* Ub = U + (size_t)(b0 + bz) * Hn * Ln;

  const int srow = lane >> 2, scol = (lane & 3) * 16;  // A staging
  const int bn = t & 63, bkg = t >> 6;                 // B staging
  const int lr = lane & 15, lk = (lane >> 4) * 8;

  f32x4 acc[4][4] = {};
  for (int k0 = 0; k0 < Hn; k0 += 32) {
#pragma unroll
    for (int I2 = 0; I2 < 4; I2++) {
      int I = 4 * w + I2;    // 0..15
      async_copy16((const char*)(Amat + (size_t)(16 * I + srow) * Hn + k0) + scol,
                   (char*)As + I * 1024);
    }
    {
      float v[8];
#pragma unroll
      for (int j = 0; j < 8; j++)
        v[j] = Ub[(size_t)(k0 + bkg * 8 + j) * Ln + n0 + bn];
      bf16x8 pk;
#pragma unroll
      for (int j = 0; j < 8; j++) pk[j] = f2bf(v[j]);
      *(bf16x8*)&Bsb[bn * 40 + bkg * 8] = pk;
    }
    __syncthreads();
    bf16x8 af[4], bfr[4];
#pragma unroll
    for (int mt = 0; mt < 4; mt++)
      af[mt] = *(const bf16x8*)&As[(64 * w + 16 * mt + lr) * 32 + lk];
#pragma unroll
    for (int nt = 0; nt < 4; nt++)
      bfr[nt] = *(const bf16x8*)&Bsb[(16 * nt + lr) * 40 + lk];
#pragma unroll
    for (int mt = 0; mt < 4; mt++)
#pragma unroll
      for (int nt = 0; nt < 4; nt++)
        acc[mt][nt] = __builtin_amdgcn_mfma_f32_16x16x32_bf16(
            af[mt], bfr[nt], acc[mt][nt], 0, 0, 0);
    __syncthreads();
  }

  // ---- fused epilogue: transpose to LDS, chunk-local scan, write xlocal (bf16) + End.
  const int row4 = (lane >> 4) * 4, col = lane & 15;
  short* Bub = Bu + (size_t)bz * Ln * 256;
  float scr = 0.f, sci = 0.f;         // scan state (threads t<128: complex p=t)
  const float Ar = Lam[t & 127], Ai = Lam[128 + (t & 127)];
#pragma unroll
  for (int pass = 0; pass < 2; pass++) {
    __syncthreads();
    // acc -> Sl[n_local][m] (n_local = l within pass's 32 rows)
#pragma unroll
    for (int mt = 0; mt < 4; mt++)
#pragma unroll
      for (int ntl = 0; ntl < 2; ntl++) {
        int nt = 2 * pass + ntl;
        *(f32x4*)&Sl[16 * ntl + col][64 * w + 16 * mt + row4] = acc[mt][nt];
      }
    __syncthreads();
    if (t < 128) {
      const int p = t;
#pragma unroll
      for (int j = 0; j < 32; j++) {
        float br = Sl[j][p], bi = Sl[j][128 + p];
        float nr = fmaf(Ar, scr, fmaf(-Ai, sci, br));
        float ni = fmaf(Ar, sci, fmaf(Ai, scr, bi));
        scr = nr; sci = ni;
        Sl[j][p] = nr; Sl[j][128 + p] = ni;
      }
    }
    __syncthreads();
    // coalesced bf16 store: 32 rows x 512B
    {
      const int row = t >> 3, seg = t & 7;
      short* dst = Bub + (size_t)(n0 + 32 * pass + row) * 256 + seg * 32;
      const float* src = &Sl[row][seg * 32];
#pragma unroll
      for (int q = 0; q < 4; q++) {
        bf16x8 pk;
#pragma unroll
        for (int j = 0; j < 8; j++) pk[j] = f2bf(src[8 * q + j]);
        *(bf16x8*)&dst[8 * q] = pk;
      }
    }
  }
  if (t < 128) {
    float* E = End + ((size_t)bz * 128 + blockIdx.x) * 256;
    E[t] = scr;
    E[128 + t] = sci;
  }
}

// ---------------------------------------------------------------- carry propagation (A64, 128 chunks)
__global__ __launch_bounds__(128) void carry_kernel(const float* __restrict__ End,
                                                    float* __restrict__ Carry,
                                                    const float* __restrict__ Lam) {
  const int bz = blockIdx.x;
  const int p = threadIdx.x;
  const float a64r = Lam[256 + p], a64i = Lam[384 + p];
  const float* E = End + (size_t)bz * 128 * 256;
  float* C = Carry + (size_t)bz * 128 * 256;
  float xr = 0.f, xi = 0.f;
  float er0[4], ei0[4], er1[4], ei1[4];
#pragma unroll
  for (int q = 0; q < 4; q++) {
    er0[q] = E[(size_t)q * 256 + p];
    ei0[q] = E[(size_t)q * 256 + 128 + p];
  }
  for (int c0 = 0; c0 < 128; c0 += 8) {
#pragma unroll
    for (int q = 0; q < 4; q++) {
      er1[q] = E[(size_t)(c0 + 4 + q) * 256 + p];
      ei1[q] = E[(size_t)(c0 + 4 + q) * 256 + 128 + p];
    }
#pragma unroll
    for (int q = 0; q < 4; q++) {
      C[(size_t)(c0 + q) * 256 + p] = xr;
      C[(size_t)(c0 + q) * 256 + 128 + p] = xi;
      float nr = fmaf(a64r, xr, fmaf(-a64i, xi, er0[q]));
      float ni = fmaf(a64r, xi, fmaf(a64i, xr, ei0[q]));
      xr = nr; xi = ni;
    }
#pragma unroll
    for (int q = 0; q < 4; q++) {
      int cn = c0 + 8 + q;
      if (cn < 128) {
        er0[q] = E[(size_t)cn * 256 + p];
        ei0[q] = E[(size_t)cn * 256 + 128 + p];
      }
    }
#pragma unroll
    for (int q = 0; q < 4; q++) {
      C[(size_t)(c0 + 4 + q) * 256 + p] = xr;
      C[(size_t)(c0 + 4 + q) * 256 + 128 + p] = xi;
      float nr = fmaf(a64r, xr, fmaf(-a64i, xi, er1[q]));
      float ni = fmaf(a64r, xi, fmaf(a64i, xr, ei1[q]));
      xr = nr; xi = ni;
    }
  }
}

// ---------------------------------------------------------------- MFMA GEMM2 (pipelined: dbuf LDS, 1 barrier/step, Cy in LDS)
// Out[b][H][L] = gelu( Cmat[512][256] @ xs^T + D[h]*U[b][h][l] )
// xs[l] = Ppow[l&63]*carry[l>>6] + xlocal[l], reconstructed in staging.
// Pipeline: issue step s+1 loads (async A + Xs/Ppow regs) BEFORE step s MFMA,
// land recon+LDS write after; one barrier per step.
__global__ __launch_bounds__(256) void gemm2_kernel(
    const __hip_bfloat16* __restrict__ Cmat,  // [512][256]
    const short* __restrict__ Xs,             // [NB][8192][256] xlocal bf16
    const float* __restrict__ Ppow,           // [64][256]
    const float* __restrict__ Cy,             // [NB][128][2][128]
    const float* __restrict__ U,              // [8][512][8192]
    const float* __restrict__ Dv,             // [512]
    float* __restrict__ Out, int b0) {
  __shared__ __align__(16) short As[2][128 * 32];   // 16 KB
  __shared__ __align__(16) short Bs[2][128 * 40];   // 20 KB (stride 40 shorts)
  __shared__ __align__(16) float CyS[512];          // [ro*256 + half*128 + p]
  const int t = threadIdx.x;
  const int lane = t & 63, w = t >> 6;
  const int wm = w >> 1, wn = w & 1;
  const int n0 = blockIdx.x * 128;
  const int m0 = blockIdx.y * 128;
  const int bz = blockIdx.z;
  const int b = b0 + bz;

  const int srow = lane >> 2, scol = (lane & 3) * 16;
  const int krow = t >> 2, kq = t & 3;       // staging: row in 64-group, 16B k-chunk
  const short* Xb = Xs + ((size_t)bz * Ln + n0) * 256;

  bf16x8 xl[2];
  f32x4 Pr[4];

  auto STAGE_A = [&](int s, int buf) {
    const int k0 = s * 32;
#pragma unroll
    for (int I2 = 0; I2 < 2; I2++) {
      int I = 2 * w + I2;
      async_copy16((const char*)(Cmat + (size_t)(m0 + 16 * I + srow) * 256 + k0) + scol,
                   (char*)As[buf] + I * 1024);
    }
  };
  auto STAGE_ISSUE = [&](int s) {
    const int kwin = s * 32 + kq * 8;
    const int p0 = kwin & 127;
#pragma unroll
    for (int ro = 0; ro < 2; ro++)
      xl[ro] = *(const bf16x8*)&Xb[(size_t)(ro * 64 + krow) * 256 + kwin];
    Pr[0] = *(const f32x4*)&Ppow[krow * 256 + p0];
    Pr[1] = *(const f32x4*)&Ppow[krow * 256 + p0 + 4];
    Pr[2] = *(const f32x4*)&Ppow[krow * 256 + 128 + p0];
    Pr[3] = *(const f32x4*)&Ppow[krow * 256 + 128 + p0 + 4];
  };
  auto STAGE_WRITE = [&](int s, int buf) {
    const int kwin = s * 32 + kq * 8;
    const bool isRe = kwin < 128;
    const int p0 = kwin & 127;
    const int ha = isRe ? 0 : 128, hb = isRe ? 128 : 0;
#pragma unroll
    for (int ro = 0; ro < 2; ro++) {
      f32x4 u0 = *(const f32x4*)&CyS[ro * 256 + ha + p0];
      f32x4 u1 = *(const f32x4*)&CyS[ro * 256 + ha + p0 + 4];
      f32x4 v0 = *(const f32x4*)&CyS[ro * 256 + hb + p0];
      f32x4 v1 = *(const f32x4*)&CyS[ro * 256 + hb + p0 + 4];
      if (isRe) { v0 = -v0; v1 = -v1; }
      bf16x8 pk;
#pragma unroll
      for (int q = 0; q < 4; q++) {
        float v = fmaf(Pr[0][q], u0[q], fmaf(Pr[2][q], v0[q], bf2f(xl[ro][q])));
        pk[q] = f2bf(v);
      }
#pragma unroll
      for (int q = 0; q < 4; q++) {
        float v = fmaf(Pr[1][q], u1[q], fmaf(Pr[3][q], v1[q], bf2f(xl[ro][4 + q])));
        pk[4 + q] = f2bf(v);
      }
      *(bf16x8*)&Bs[buf][(ro * 64 + krow) * 40 + kq * 8] = pk;
    }
  };

  // prologue: issue step-0 loads, fill CyS, then write step 0
  STAGE_A(0, 0);
  STAGE_ISSUE(0);
  {
    const float* Cyb = Cy + ((size_t)bz * 128 + (n0 >> 6)) * 256;
    CyS[t] = Cyb[t];
    CyS[256 + t] = Cyb[256 + t];
  }
  __syncthreads();            // CyS visible (vmcnt drained: A0 landed too)
  STAGE_WRITE(0, 0);
  __syncthreads();            // Bs[0] ready

  const int lr = lane & 15, lk = (lane >> 4) * 8;
  f32x4 acc[4][4] = {};
#pragma unroll
  for (int s = 0; s < 8; s++) {
    const int cur = s & 1;
    if (s < 7) {
      STAGE_A(s + 1, cur ^ 1);     // async -> other buffer
      STAGE_ISSUE(s + 1);          // global loads in flight during MFMA
    }
    bf16x8 af[4], bfr[4];
#pragma unroll
    for (int mt = 0; mt < 4; mt++)
      af[mt] = *(const bf16x8*)&As[cur][(64 * wm + 16 * mt + lr) * 32 + lk];
#pragma unroll
    for (int nt = 0; nt < 4; nt++)
      bfr[nt] = *(const bf16x8*)&Bs[cur][(64 * wn + 16 * nt + lr) * 40 + lk];
#pragma unroll
    for (int mt = 0; mt < 4; mt++)
#pragma unroll
      for (int nt = 0; nt < 4; nt++)
        acc[mt][nt] = __builtin_amdgcn_mfma_f32_16x16x32_bf16(
            af[mt], bfr[nt], acc[mt][nt], 0, 0, 0);
    if (s < 7) STAGE_WRITE(s + 1, cur ^ 1);
    __syncthreads();               // drains vmcnt (A s+1) + orders Bs writes
  }

  const int row4 = (lane >> 4) * 4, col = lane & 15;
#pragma unroll
  for (int mt = 0; mt < 4; mt++) {
#pragma unroll
    for (int r = 0; r < 4; r++) {
      int h = m0 + 64 * wm + 16 * mt + row4 + r;
      float dh = Dv[h];
      const float* Urow = U + ((size_t)b * Hn + h) * Ln;
      float* Orow = Out + ((size_t)b * Hn + h) * Ln;
#pragma unroll
      for (int nt = 0; nt < 4; nt++) {
        int n = n0 + 64 * wn + 16 * nt + col;
        float y = acc[mt][nt][r] + dh * Urow[n];
        // tanh-form gelu: y * sigmoid(2*0.7978845608*(y + 0.044715 y^3)), tail-safe
        float u2 = y * (0.7978845608f + 0.0356774081f * y * y);
        Orow[n] = y / (1.0f + __expf(-2.0f * u2));
      }
    }
  }
}

// ---------------------------------------------------------------- launch
extern "C" void kernel_launch(void* const* d_in, const int* in_sizes, int n_in,
                              void* d_out, int out_size, void* d_ws, size_t ws_size,
                              hipStream_t stream) {
  const float* U   = (const float*)d_in[0];
  const float* Lre = (const float*)d_in[1];
  const float* Lim = (const float*)d_in[2];
  const float* Bin = (const float*)d_in[3];
  const float* Cin = (const float*)d_in[4];
  const float* Dv  = (const float*)d_in[5];
  const float* ls  = (const float*)d_in[6];
  float* out = (float*)d_out;

  char* wsb = (char*)d_ws;
  float* Lam = (float*)wsb;
  __hip_bfloat16* Bmat = (__hip_bfloat16*)(wsb + OFF_BMAT);
  __hip_bfloat16* Cmat = (__hip_bfloat16*)(wsb + OFF_CMAT);
  float* Ppow = (float*)(wsb + OFF_PPOW);
  float* End = (float*)(wsb + OFF_END);
  float* Cy  = (float*)(wsb + OFF_CAR);
  short* Bu  = (short*)(wsb + HEADB);

  int NB = 8;
  while (NB > 1 && ws_size < HEADB + (size_t)NB * SZ_BU)
    NB >>= 1;

  precompute_kernel<<<(4 * Pn * Hn + 512 + 64 * 256 + 255) / 256, 256, 0, stream>>>(
      Lre, Lim, Bin, Cin, ls, Lam, Bmat, Cmat, Ppow);

  for (int b0 = 0; b0 < BS; b0 += NB) {
    gemm1_kernel<<<dim3(Ln / 64, 1, NB), 256, 0, stream>>>(Bmat, U, Bu, End, Lam, b0);
    carry_kernel<<<dim3(NB), 128, 0, stream>>>(End, Cy, Lam);
    gemm2_kernel<<<dim3(Ln / 128, Hn / 128, NB), 256, 0, stream>>>(
        Cmat, Bu, Ppow, Cy, U, Dv, out, b0);
  }
}